// Round 5
// baseline (1082.866 us; speedup 1.0000x reference)
//
#include <hip/hip_runtime.h>

typedef unsigned short u16;
typedef __bf16 bf16x8 __attribute__((ext_vector_type(8)));
typedef float floatx4 __attribute__((ext_vector_type(4)));
typedef unsigned short u16x8 __attribute__((ext_vector_type(8)));

#define C_  256
#define NTOK 131072                  // B*D*H*W = 8*4*64*64
#define QS2 0.25503488f              // 1/sqrt(32) * log2(e)
#define LOG2E 1.4426950408889634f

// ws: two bf16 regions of NTOK*256 elems.
// r0: xw -> q (in-place) -> o (in-place) -> oproj (in-place) -> h1
// r1: xn -> h2 (in-place)
// d_out: [k | vT] bf16 halves during attention, then y fp32 (RMW'd into out).
#define R1_ELEMS 33554432ull

// All weights, pre-converted to bf16 B^T, in a static device buffer (1 MB).
// offsets (u16 elems): wq 0, wkv 65536, wp 196608, w1 262144, w2 393216
__device__ u16 g_wT[524288];
// Precomputed attention bias (window-independent), pre-scaled by log2(e), bf16.
// layout: [i][h][wave][lq][lr][t][r]  = (((i*8+h)*256 + wave*64+lq*16+lr))*48 + t*4 + r
__device__ u16 g_bexp[393216];       // 4*8*64*192

__device__ __forceinline__ float bf2f(u16 u) {
    return __uint_as_float(((unsigned)u) << 16);
}
// native RNE convert: compiler emits v_cvt_pk_bf16_f32 (1 op vs 4-op bit-twiddle)
__device__ __forceinline__ u16 f2bf(float f) {
    union { __bf16 h; u16 u; } c; c.h = (__bf16)f; return c.u;
}

// async global->LDS, 16B per lane. LDS dest is wave-uniform base + lane*16;
// our LDS layouts are lane-linear so dest == base + lane*16 by construction.
#define GL16(gsrc, ldst) __builtin_amdgcn_global_load_lds(                    \
    (const __attribute__((address_space(1))) void*)(gsrc),                    \
    (__attribute__((address_space(3))) void*)(ldst), 16, 0, 0)

// ------------------------------------------------- weight convert fp32->bf16 B^T
// W fp32 [Kd][N] row-major -> g_wT[ofs + n*Kd + k], Kd = 1<<ks.
__global__ __launch_bounds__(256) void wcvt_kernel(
    const float* __restrict__ W, int N, int ks, int ofs)
{
    const int idx = blockIdx.x * 256 + threadIdx.x;
    const int n = idx >> ks;
    const int k = idx & ((1 << ks) - 1);
    g_wT[ofs + idx] = f2bf(W[(size_t)k * N + n]);
}

// ------------------------------------------------- bias expand (once)
// grid 32 = (i*8+h). Per (i,h): fill per-lane-contiguous [wave][lq][lr][t][r].
__global__ __launch_bounds__(256) void bexp_kernel(const float* __restrict__ rpb)
{
    const int i = blockIdx.x >> 3, h = blockIdx.x & 7;
    const int tf = threadIdx.x;
    const int w = tf >> 6, lq = (tf >> 4) & 3, lr = tf & 15;
    u16* dst = &g_bexp[((size_t)(blockIdx.x * 256 + tf)) * 48];
#pragma unroll
    for (int t = 0; t < 12; ++t) {
        const int kl = t * 16 + lr;
        const int nk = (kl < i * 64) ? kl : kl + 64;
        const int dk = nk >> 6, hk = (nk >> 3) & 7, wk = nk & 7;
#pragma unroll
        for (int r = 0; r < 4; ++r) {
            const int q = w * 16 + lq * 4 + r;
            const int hq = q >> 3, wq = q & 7;
            const int rel = (i - dk + 3) * 225 + (hq - hk + 7) * 15 + (wq - wk + 7);
            dst[t * 4 + r] = f2bf(rpb[rel * 8 + h] * LOG2E);
        }
    }
}

// ---------------------------------------------------------- LN1 + partition
__global__ __launch_bounds__(256) void ln_part_kernel(
    const float* __restrict__ x, const float* __restrict__ g, const float* __restrict__ bb,
    u16* __restrict__ xw)
{
    const int lane = threadIdx.x & 63;
    const int wave = threadIdx.x >> 6;
    const int t = blockIdx.x * 4 + wave;          // window row: wb*256+n
    const int wb = t >> 8, n = t & 255;
    const int bidx = wb >> 6, hb = (wb >> 3) & 7, wbl = wb & 7;
    const int d = n >> 6, hh = (n >> 3) & 7, ww = n & 7;
    const size_t src = ((((size_t)bidx * 4 + d) * 64 + hb * 8 + hh) * 64 + wbl * 8 + ww) * C_;
    const int c0 = lane * 4;
    float4 raw = *reinterpret_cast<const float4*>(&x[src + c0]);
    float v0 = raw.x, v1 = raw.y, v2 = raw.z, v3 = raw.w;
    float s = v0 + v1 + v2 + v3;
    float sq = v0 * v0 + v1 * v1 + v2 * v2 + v3 * v3;
#pragma unroll
    for (int off = 32; off > 0; off >>= 1) {
        s  += __shfl_xor(s, off, 64);
        sq += __shfl_xor(sq, off, 64);
    }
    const float mean = s * (1.0f / 256.0f);
    const float var  = sq * (1.0f / 256.0f) - mean * mean;
    const float rstd = rsqrtf(var + 1e-5f);
    float4 gr = *reinterpret_cast<const float4*>(&g[c0]);
    float4 br = *reinterpret_cast<const float4*>(&bb[c0]);
    ushort4 outv;
    outv.x = f2bf((v0 - mean) * rstd * gr.x + br.x);
    outv.y = f2bf((v1 - mean) * rstd * gr.y + br.y);
    outv.z = f2bf((v2 - mean) * rstd * gr.z + br.z);
    outv.w = f2bf((v3 - mean) * rstd * gr.w + br.w);
    *reinterpret_cast<ushort4*>(&xw[(size_t)t * C_ + c0]) = outv;
}

// ------------------------------------------------- residual + LN2
__global__ __launch_bounds__(256) void resid_ln2_kernel(
    const float* __restrict__ x, const u16* __restrict__ oproj,
    const float* __restrict__ g, const float* __restrict__ bb,
    float* __restrict__ y, u16* __restrict__ xn)
{
    const int lane = threadIdx.x & 63;
    const int wave = threadIdx.x >> 6;
    const int t = blockIdx.x * 4 + wave;          // x-layout token
    const int wpos = t & 63;
    const int h = (t >> 6) & 63;
    const int d = (t >> 12) & 3;
    const int bidx = t >> 14;
    const int wr = (((bidx * 8) + (h >> 3)) * 8 + (wpos >> 3)) * 256
                 + d * 64 + (h & 7) * 8 + (wpos & 7);   // window row
    const int c0 = lane * 4;
    float4 xr = *reinterpret_cast<const float4*>(&x[(size_t)t * C_ + c0]);
    ushort4 pr = *reinterpret_cast<const ushort4*>(&oproj[(size_t)wr * C_ + c0]);
    float v0 = xr.x + bf2f(pr.x);
    float v1 = xr.y + bf2f(pr.y);
    float v2 = xr.z + bf2f(pr.z);
    float v3 = xr.w + bf2f(pr.w);
    float s = v0 + v1 + v2 + v3;
    float sq = v0 * v0 + v1 * v1 + v2 * v2 + v3 * v3;
#pragma unroll
    for (int off = 32; off > 0; off >>= 1) {
        s  += __shfl_xor(s, off, 64);
        sq += __shfl_xor(sq, off, 64);
    }
    const float mean = s * (1.0f / 256.0f);
    const float var  = sq * (1.0f / 256.0f) - mean * mean;
    const float rstd = rsqrtf(var + 1e-5f);
    float4 yv; yv.x = v0; yv.y = v1; yv.z = v2; yv.w = v3;
    *reinterpret_cast<float4*>(&y[(size_t)t * C_ + c0]) = yv;
    float4 gr = *reinterpret_cast<const float4*>(&g[c0]);
    float4 br = *reinterpret_cast<const float4*>(&bb[c0]);
    ushort4 nv;
    nv.x = f2bf((v0 - mean) * rstd * gr.x + br.x);
    nv.y = f2bf((v1 - mean) * rstd * gr.y + br.y);
    nv.z = f2bf((v2 - mean) * rstd * gr.z + br.z);
    nv.w = f2bf((v3 - mean) * rstd * gr.w + br.w);
    *reinterpret_cast<ushort4*>(&xn[(size_t)t * C_ + c0]) = nv;
}

// ----------------------------------------------------------- MFMA bf16 GEMM v3
// M=NTOK, N=256, K=kdim (256 or 512). BM=64, BN=256, BK=32; 4 waves, wave w
// owns cols [w*64, w*64+64), acc[4][4]. One block per 64-row strip.
// mode: 0 plain->Cm, 1 +bias->Cm, 2 +bias+GELU->Cm, 5 Cf += acc + bias,
//       7 transposed store: Cm is [256][NTOK], Cm[col][row] = bf16(acc).
// LDS 40960 B = exactly 4 blocks/CU; launch_bounds(256,4) targets that.
__global__ __launch_bounds__(256, 4) void gemm_v3_kernel(
    const u16* __restrict__ A, const u16* __restrict__ A2,
    int bofs, int kdim,
    u16* __restrict__ Cm, float* __restrict__ Cf, const float* __restrict__ bias,
    int mode)
{
    // per buffer (u16 elems): A tile [64][32] at 0 (2048), B tile [256][32] at 2048 (8192)
    __shared__ __align__(16) u16 lds[2 * 10240];   // 40 KiB
    const int tid  = threadIdx.x;
    const int lane = tid & 63, wave = tid >> 6;
    const int lr = lane & 15, lq = lane >> 4;
    const int row0 = blockIdx.x * 64;
    const u16* Bt = &g_wT[bofs];

    const int s_row = lane >> 2;          // 0..15 within a 16-row segment
    const int s_kel = (lane & 3) * 8;     // k-element offset within 32

    floatx4 acc[4][4] = {};
    const int NK = kdim >> 5;
    int cur = 0;

    // ---- stage one K-step into buffer buf (5x global_load_lds per thread)
    auto STAGE = [&](int buf, int ks) {
        const int k0 = ks << 5;
        const u16* Asrc = A;
        int ka = k0;
        if (k0 >= 256) { Asrc = A2; ka = k0 - 256; }
        u16* lb = &lds[buf * 10240];
        // A: segment = wave (16 rows); lane-linear: elem = wave*512 + lane*8
        GL16(&Asrc[(size_t)(row0 + wave * 16 + s_row) * 256 + ka + s_kel],
             lb + wave * 512 + lane * 8);
        // B: segments s = wave*4+c (16 B^T-rows each)
#pragma unroll
        for (int c = 0; c < 4; ++c) {
            const int s = wave * 4 + c;
            GL16(&Bt[(size_t)(s * 16 + s_row) * kdim + k0 + s_kel],
                 lb + 2048 + s * 512 + lane * 8);
        }
    };

    STAGE(0, 0);
    __syncthreads();                      // drains vmcnt; buf0 ready

    for (int ks = 0; ks < NK; ++ks) {
        if (ks + 1 < NK) STAGE(cur ^ 1, ks + 1);   // issue-early: flies under compute
        const u16* lb = &lds[cur * 10240];
        bf16x8 af[4], bfv[4];
#pragma unroll
        for (int mt = 0; mt < 4; ++mt)
            af[mt] = *reinterpret_cast<const bf16x8*>(lb + (mt * 16 + lr) * 32 + lq * 8);
#pragma unroll
        for (int nt = 0; nt < 4; ++nt)
            bfv[nt] = *reinterpret_cast<const bf16x8*>(
                lb + 2048 + (wave * 64 + nt * 16 + lr) * 32 + lq * 8);
#pragma unroll
        for (int mt = 0; mt < 4; ++mt)
#pragma unroll
            for (int nt = 0; nt < 4; ++nt)
                acc[mt][nt] = __builtin_amdgcn_mfma_f32_16x16x32_bf16(
                    af[mt], bfv[nt], acc[mt][nt], 0, 0, 0);
        __syncthreads();                  // drains next-stage vmcnt + barrier
        cur ^= 1;
    }

    if (mode == 7) {
        // transposed bf16 store, direct from acc (8B per (mt,nt))
#pragma unroll
        for (int mt = 0; mt < 4; ++mt)
#pragma unroll
            for (int nt = 0; nt < 4; ++nt) {
                const int col = wave * 64 + nt * 16 + lr;
                const size_t tok = (size_t)row0 + mt * 16 + lq * 4;
                ushort4 st;
                st.x = f2bf(acc[mt][nt][0]);
                st.y = f2bf(acc[mt][nt][1]);
                st.z = f2bf(acc[mt][nt][2]);
                st.w = f2bf(acc[mt][nt][3]);
                *reinterpret_cast<ushort4*>(&Cm[(size_t)col * NTOK + tok]) = st;
            }
        return;
    }

    // ---- epilogue: per-wave LDS transpose slice (16 rows x 68 fp32, 4 passes)
    float* tw = reinterpret_cast<float*>(&lds[0]) + wave * (16 * 68);
#pragma unroll
    for (int mt = 0; mt < 4; ++mt) {
        asm volatile("s_waitcnt lgkmcnt(0)" ::: "memory");   // WAR vs prev pass reads
        __builtin_amdgcn_sched_barrier(0);
#pragma unroll
        for (int nt = 0; nt < 4; ++nt) {
            const int col = wave * 64 + nt * 16 + lr;
            const float bs = (mode != 0) ? bias[col] : 0.0f;
#pragma unroll
            for (int r = 0; r < 4; ++r) {
                float v = acc[mt][nt][r] + bs;
                if (mode == 2) v = 0.5f * v * (1.0f + erff(v * 0.70710678118654752f));
                tw[(lq * 4 + r) * 68 + nt * 16 + lr] = v;
            }
        }
        asm volatile("s_waitcnt lgkmcnt(0)" ::: "memory");   // writes visible to wave
        __builtin_amdgcn_sched_barrier(0);
        const int rrow = lane >> 2, grp = lane & 3;
        const float* src = &tw[rrow * 68 + grp * 16];
        float4 f0 = *reinterpret_cast<const float4*>(src + 0);
        float4 f1 = *reinterpret_cast<const float4*>(src + 4);
        float4 f2 = *reinterpret_cast<const float4*>(src + 8);
        float4 f3 = *reinterpret_cast<const float4*>(src + 12);
        const size_t gofs = (size_t)(row0 + mt * 16 + rrow) * 256 + wave * 64 + grp * 16;
        if (mode == 5) {
            float4* cp = reinterpret_cast<float4*>(&Cf[gofs]);
            float4 c0 = cp[0], c1 = cp[1], c2 = cp[2], c3 = cp[3];
            c0.x += f0.x; c0.y += f0.y; c0.z += f0.z; c0.w += f0.w;
            c1.x += f1.x; c1.y += f1.y; c1.z += f1.z; c1.w += f1.w;
            c2.x += f2.x; c2.y += f2.y; c2.z += f2.z; c2.w += f2.w;
            c3.x += f3.x; c3.y += f3.y; c3.z += f3.z; c3.w += f3.w;
            cp[0] = c0; cp[1] = c1; cp[2] = c2; cp[3] = c3;
        } else {
            const float tf[16] = {f0.x, f0.y, f0.z, f0.w, f1.x, f1.y, f1.z, f1.w,
                                  f2.x, f2.y, f2.z, f2.w, f3.x, f3.y, f3.z, f3.w};
            u16x8 o0, o1;
#pragma unroll
            for (int j = 0; j < 8; ++j) { o0[j] = f2bf(tf[j]); o1[j] = f2bf(tf[j + 8]); }
            *reinterpret_cast<u16x8*>(&Cm[gofs])     = o0;
            *reinterpret_cast<u16x8*>(&Cm[gofs + 8]) = o1;
        }
    }
}

// -------------------------------------------------------------- attention v3
// Barrier-free, latency-optimized. block = (window wb, slice i), XCD-swizzled.
// 4 waves; wave w owns q-rows [16w,16w+16). All MFMA fragments direct from
// global (L2): Q/K rows, V^T rows. Bias from g_bexp (6x16B per lane).
// Softmax in log2 domain, normalization deferred to O (8 mults vs 48).
// Only LDS: wave-private P roundtrip. 25.6 KB -> 6 blocks/CU.
__global__ __launch_bounds__(256, 6) void attn_kernel(
    u16* __restrict__ qo, const u16* __restrict__ kb, const u16* __restrict__ vT)
{
    __shared__ __align__(16) u16 sp[64][200];    // [q][key] P, bf16 (wave-private rows)

    const int bid = blockIdx.x;
    const int i  = (bid >> 3) & 3;
    const int wb = (bid & 7) + (bid >> 5) * 8;   // XCD = wb % 8
    const int tid = threadIdx.x;
    const int lane = tid & 63, wave = tid >> 6;
    const int lr = lane & 15, lq = lane >> 4;
    const size_t qbase = ((size_t)(wb * 256 + i * 64)) * C_;
    const size_t kwin  = ((size_t)(wb * 256)) * C_;
    const u16* bx = &g_bexp[((size_t)((i * 8) * 256) + (size_t)(wave * 64 + lq * 16 + lr)) * 48];

    for (int h = 0; h < 8; ++h) {
        const int hc = h * 32;
        // ---- bias fragment: 48 bf16 contiguous per lane
        u16x8 bvv[6];
        {
            const u16* bl = bx + (size_t)h * 256 * 48;
#pragma unroll
            for (int v = 0; v < 6; ++v)
                bvv[v] = *reinterpret_cast<const u16x8*>(bl + v * 8);
        }
        // ---- QK^T: A = own q rows, B = key rows (12 tiles), direct global
        const bf16x8 af = *reinterpret_cast<const bf16x8*>(
            &qo[qbase + (size_t)(wave * 16 + lr) * C_ + hc + lq * 8]);
        floatx4 acc[12];
        __builtin_amdgcn_s_setprio(1);
#pragma unroll
        for (int t = 0; t < 12; ++t) {
            const int nrow = t * 16 + ((t * 16 >= i * 64) ? 64 : 0) + lr;
            const bf16x8 bk = *reinterpret_cast<const bf16x8*>(
                &kb[kwin + (size_t)nrow * C_ + hc + lq * 8]);
            acc[t] = __builtin_amdgcn_mfma_f32_16x16x32_bf16(
                af, bk, (floatx4){0.f, 0.f, 0.f, 0.f}, 0, 0, 0);
        }
        __builtin_amdgcn_s_setprio(0);
        // ---- scale (log2 domain) + bias, row max
        float mrow[4] = {-1e30f, -1e30f, -1e30f, -1e30f};
#pragma unroll
        for (int t = 0; t < 12; ++t)
#pragma unroll
            for (int r = 0; r < 4; ++r) {
                const int ii = t * 4 + r;
                const float v = fmaf(acc[t][r], QS2, bf2f((u16)bvv[ii >> 3][ii & 7]));
                acc[t][r] = v;
                mrow[r] = fmaxf(mrow[r], v);
            }
#pragma unroll
        for (int off = 8; off >= 1; off >>= 1)
#pragma unroll
            for (int r = 0; r < 4; ++r)
                mrow[r] = fmaxf(mrow[r], __shfl_xor(mrow[r], off, 64));
        // ---- exp2 + row sum (P left unnormalized; values in (0,1])
        float srow[4] = {0.f, 0.f, 0.f, 0.f};
#pragma unroll
        for (int t = 0; t < 12; ++t)
#pragma unroll
            for (int r = 0; r < 4; ++r) {
                const float e = exp2f(acc[t][r] - mrow[r]);
                acc[t][r] = e;
                srow[r] += e;
            }
#pragma unroll
        for (int off = 8; off >= 1; off >>= 1)
#pragma unroll
            for (int r = 0; r < 4; ++r)
                srow[r] += __shfl_xor(srow[r], off, 64);
#pragma unroll
        for (int r = 0; r < 4; ++r) srow[r] = 1.0f / srow[r];
        // ---- unnormalized P -> LDS (wave-private rows; no barrier needed)
#pragma unroll
        for (int t = 0; t < 12; ++t)
#pragma unroll
            for (int r = 0; r < 4; ++r)
                sp[wave * 16 + lq * 4 + r][t * 16 + lr] = f2bf(acc[t][r]);
        // ---- PV: A = P rows (LDS), B = V^T rows (direct global)
        floatx4 oacc[2];
        oacc[0] = (floatx4){0.f, 0.f, 0.f, 0.f};
        oacc[1] = (floatx4){0.f, 0.f, 0.f, 0.f};
        __builtin_amdgcn_s_setprio(1);
#pragma unroll
        for (int kc = 0; kc < 6; ++kc) {
            const bf16x8 pa = *reinterpret_cast<const bf16x8*>(
                &sp[wave * 16 + lr][kc * 32 + lq * 8]);
            const int kst = kc * 32 + lq * 8;
            const int nk0 = kst + ((kst >= i * 64) ? 64 : 0);
#pragma unroll
            for (int nt = 0; nt < 2; ++nt) {
                const bf16x8 bv = *reinterpret_cast<const bf16x8*>(
                    &vT[(size_t)(hc + nt * 16 + lr) * NTOK + wb * 256 + nk0]);
                oacc[nt] = __builtin_amdgcn_mfma_f32_16x16x32_bf16(pa, bv, oacc[nt], 0, 0, 0);
            }
        }
        __builtin_amdgcn_s_setprio(0);
        // ---- normalize O (deferred 1/srow) + write over q columns for head h
#pragma unroll
        for (int nt = 0; nt < 2; ++nt)
#pragma unroll
            for (int r = 0; r < 4; ++r)
                qo[qbase + (size_t)(wave * 16 + lq * 4 + r) * C_ + hc + nt * 16 + lr] =
                    f2bf(oacc[nt][r] * srow[r]);
    }
}

// ----------------------------------------------------------------- launch
extern "C" void kernel_launch(void* const* d_in, const int* in_sizes, int n_in,
                              void* d_out, int out_size, void* d_ws, size_t ws_size,
                              hipStream_t stream) {
    const float* x    = (const float*)d_in[0];
    const float* ln1g = (const float*)d_in[1];
    const float* ln1b = (const float*)d_in[2];
    const float* ln2g = (const float*)d_in[3];
    const float* ln2b = (const float*)d_in[4];
    const float* wq   = (const float*)d_in[5];
    const float* wkv  = (const float*)d_in[6];
    const float* wp   = (const float*)d_in[7];
    const float* bp   = (const float*)d_in[8];
    const float* rpb  = (const float*)d_in[9];
    const float* w1   = (const float*)d_in[10];
    const float* b1   = (const float*)d_in[11];
    const float* w2   = (const float*)d_in[12];
    const float* b2   = (const float*)d_in[13];
    float* outf = (float*)d_out;
    u16*   outu = (u16*)d_out;          // bf16 scratch view: [k | vT]
    u16*   ws16 = (u16*)d_ws;

    u16* r0 = ws16;                     // xw -> q -> o -> oproj -> h1
    u16* r1 = ws16 + R1_ELEMS;          // xn -> h2 (in-place)
    u16* kbuf = outu;
    u16* vTb  = outu + R1_ELEMS;        // V^T [256][NTOK]

    // 0. convert weights to bf16 B^T into g_wT; expand bias table (once per launch)
    wcvt_kernel<<<256, 256, 0, stream>>>(wq,  256, 8, 0);
    wcvt_kernel<<<512, 256, 0, stream>>>(wkv, 512, 8, 65536);
    wcvt_kernel<<<256, 256, 0, stream>>>(wp,  256, 8, 196608);
    wcvt_kernel<<<512, 256, 0, stream>>>(w1,  512, 8, 262144);
    wcvt_kernel<<<512, 256, 0, stream>>>(w2,  256, 9, 393216);
    bexp_kernel<<<32, 256, 0, stream>>>(rpb);

    // 1. LN1 + window partition (fp32 -> bf16)
    ln_part_kernel<<<NTOK / 4, 256, 0, stream>>>(x, ln1g, ln1b, r0);

    // 2. k = xw @ wkv[:,0:256] -> kbuf; v^T = (xw @ wkv[:,256:512])^T -> vTb
    gemm_v3_kernel<<<NTOK / 64, 256, 0, stream>>>(r0, r0, 65536,  256, kbuf, nullptr, nullptr, 0);
    gemm_v3_kernel<<<NTOK / 64, 256, 0, stream>>>(r0, r0, 131072, 256, vTb,  nullptr, nullptr, 7);
    // 3. q = xw @ wq -> r0 (in-place)
    gemm_v3_kernel<<<NTOK / 64, 256, 0, stream>>>(r0, r0, 0, 256, r0, nullptr, nullptr, 0);

    // 4. attention: o overwrites q in r0 (barrier-free, XCD-swizzled)
    attn_kernel<<<2048, 256, 0, stream>>>(r0, kbuf, vTb);

    // 5. oproj = o @ wp + bp -> r0 (in-place)
    gemm_v3_kernel<<<NTOK / 64, 256, 0, stream>>>(r0, r0, 196608, 256, r0, nullptr, bp, 1);

    // 6. y = x + reverse(oproj) -> d_out fp32 (k,vT dead); xn = LN2(y) -> r1
    resid_ln2_kernel<<<NTOK / 4, 256, 0, stream>>>(x, r0, ln2g, ln2b, outf, r1);

    // 7. MLP: h1 -> r0 (oproj dead), h2 -> r1 in-place over xn,
    //    then single K=512 GEMM: out = y + [h1|h2] @ w2^T + b2 (fp32 RMW once)
    gemm_v3_kernel<<<NTOK / 64, 256, 0, stream>>>(r1, r1, 262144, 256, r0, nullptr, b1,       2);
    gemm_v3_kernel<<<NTOK / 64, 256, 0, stream>>>(r1, r1, 327680, 256, r1, nullptr, b1 + 256, 2);
    gemm_v3_kernel<<<NTOK / 64, 256, 0, stream>>>(r0, r1, 393216, 512, nullptr, outf, b2,     5);
}

// Round 6
// 937.907 us; speedup vs baseline: 1.1546x; 1.1546x over previous
//
#include <hip/hip_runtime.h>

typedef unsigned short u16;
typedef __bf16 bf16x8 __attribute__((ext_vector_type(8)));
typedef float floatx4 __attribute__((ext_vector_type(4)));
typedef unsigned short u16x8 __attribute__((ext_vector_type(8)));

#define C_  256
#define NTOK 131072                  // B*D*H*W = 8*4*64*64
#define QS2 0.25503488f              // 1/sqrt(32) * log2(e)
#define LOG2E 1.4426950408889634f

// ws: two bf16 regions of NTOK*256 elems.
// r0: xw -> q (in-place) -> oproj -> h1
// r1: o -> xn (in-place) -> h2 (in-place)
// d_out: [k | vT] bf16 halves during attention, then y fp32 (RMW'd into out).
#define R1_ELEMS 33554432ull

// All weights, pre-converted to bf16 B^T, in a static device buffer (1 MB).
// offsets (u16 elems): wq 0, wkv 65536, wp 196608, w1 262144, w2 393216
__device__ u16 g_wT[524288];
// Precomputed attention bias (window-independent), pre-scaled by log2(e), bf16.
// layout: [i][h][wave][lq][lr][t][r]  = (((i*8+h)*256 + wave*64+lq*16+lr))*48 + t*4 + r
__device__ u16 g_bexp[393216];       // 4*8*64*192

__device__ __forceinline__ float bf2f(u16 u) {
    return __uint_as_float(((unsigned)u) << 16);
}
// native RNE convert: compiler emits v_cvt_pk_bf16_f32 (1 op vs 4-op bit-twiddle)
__device__ __forceinline__ u16 f2bf(float f) {
    union { __bf16 h; u16 u; } c; c.h = (__bf16)f; return c.u;
}

// async global->LDS, 16B per lane. LDS dest is wave-uniform base + lane*16;
// our LDS layouts are lane-linear so dest == base + lane*16 by construction.
#define GL16(gsrc, ldst) __builtin_amdgcn_global_load_lds(                    \
    (const __attribute__((address_space(1))) void*)(gsrc),                    \
    (__attribute__((address_space(3))) void*)(ldst), 16, 0, 0)

// ------------------------------------------------- weight convert fp32->bf16 B^T
// W fp32 [Kd][N] row-major -> g_wT[ofs + n*Kd + k], Kd = 1<<ks.
__global__ __launch_bounds__(256) void wcvt_kernel(
    const float* __restrict__ W, int N, int ks, int ofs)
{
    const int idx = blockIdx.x * 256 + threadIdx.x;
    const int n = idx >> ks;
    const int k = idx & ((1 << ks) - 1);
    g_wT[ofs + idx] = f2bf(W[(size_t)k * N + n]);
}

// ------------------------------------------------- bias expand (once)
// grid 32 = (i*8+h). Per (i,h): fill per-lane-contiguous [wave][lq][lr][t][r].
__global__ __launch_bounds__(256) void bexp_kernel(const float* __restrict__ rpb)
{
    const int i = blockIdx.x >> 3, h = blockIdx.x & 7;
    const int tf = threadIdx.x;
    const int w = tf >> 6, lq = (tf >> 4) & 3, lr = tf & 15;
    u16* dst = &g_bexp[((size_t)(blockIdx.x * 256 + tf)) * 48];
#pragma unroll
    for (int t = 0; t < 12; ++t) {
        const int kl = t * 16 + lr;
        const int nk = (kl < i * 64) ? kl : kl + 64;
        const int dk = nk >> 6, hk = (nk >> 3) & 7, wk = nk & 7;
#pragma unroll
        for (int r = 0; r < 4; ++r) {
            const int q = w * 16 + lq * 4 + r;
            const int hq = q >> 3, wq = q & 7;
            const int rel = (i - dk + 3) * 225 + (hq - hk + 7) * 15 + (wq - wk + 7);
            dst[t * 4 + r] = f2bf(rpb[rel * 8 + h] * LOG2E);
        }
    }
}

// ---------------------------------------------------------- LN1 + partition
__global__ __launch_bounds__(256) void ln_part_kernel(
    const float* __restrict__ x, const float* __restrict__ g, const float* __restrict__ bb,
    u16* __restrict__ xw)
{
    const int lane = threadIdx.x & 63;
    const int wave = threadIdx.x >> 6;
    const int t = blockIdx.x * 4 + wave;          // window row: wb*256+n
    const int wb = t >> 8, n = t & 255;
    const int bidx = wb >> 6, hb = (wb >> 3) & 7, wbl = wb & 7;
    const int d = n >> 6, hh = (n >> 3) & 7, ww = n & 7;
    const size_t src = ((((size_t)bidx * 4 + d) * 64 + hb * 8 + hh) * 64 + wbl * 8 + ww) * C_;
    const int c0 = lane * 4;
    float4 raw = *reinterpret_cast<const float4*>(&x[src + c0]);
    float v0 = raw.x, v1 = raw.y, v2 = raw.z, v3 = raw.w;
    float s = v0 + v1 + v2 + v3;
    float sq = v0 * v0 + v1 * v1 + v2 * v2 + v3 * v3;
#pragma unroll
    for (int off = 32; off > 0; off >>= 1) {
        s  += __shfl_xor(s, off, 64);
        sq += __shfl_xor(sq, off, 64);
    }
    const float mean = s * (1.0f / 256.0f);
    const float var  = sq * (1.0f / 256.0f) - mean * mean;
    const float rstd = rsqrtf(var + 1e-5f);
    float4 gr = *reinterpret_cast<const float4*>(&g[c0]);
    float4 br = *reinterpret_cast<const float4*>(&bb[c0]);
    ushort4 outv;
    outv.x = f2bf((v0 - mean) * rstd * gr.x + br.x);
    outv.y = f2bf((v1 - mean) * rstd * gr.y + br.y);
    outv.z = f2bf((v2 - mean) * rstd * gr.z + br.z);
    outv.w = f2bf((v3 - mean) * rstd * gr.w + br.w);
    *reinterpret_cast<ushort4*>(&xw[(size_t)t * C_ + c0]) = outv;
}

// ------------------------------------------------- residual + LN2
__global__ __launch_bounds__(256) void resid_ln2_kernel(
    const float* __restrict__ x, const u16* __restrict__ oproj,
    const float* __restrict__ g, const float* __restrict__ bb,
    float* __restrict__ y, u16* __restrict__ xn)
{
    const int lane = threadIdx.x & 63;
    const int wave = threadIdx.x >> 6;
    const int t = blockIdx.x * 4 + wave;          // x-layout token
    const int wpos = t & 63;
    const int h = (t >> 6) & 63;
    const int d = (t >> 12) & 3;
    const int bidx = t >> 14;
    const int wr = (((bidx * 8) + (h >> 3)) * 8 + (wpos >> 3)) * 256
                 + d * 64 + (h & 7) * 8 + (wpos & 7);   // window row
    const int c0 = lane * 4;
    float4 xr = *reinterpret_cast<const float4*>(&x[(size_t)t * C_ + c0]);
    ushort4 pr = *reinterpret_cast<const ushort4*>(&oproj[(size_t)wr * C_ + c0]);
    float v0 = xr.x + bf2f(pr.x);
    float v1 = xr.y + bf2f(pr.y);
    float v2 = xr.z + bf2f(pr.z);
    float v3 = xr.w + bf2f(pr.w);
    float s = v0 + v1 + v2 + v3;
    float sq = v0 * v0 + v1 * v1 + v2 * v2 + v3 * v3;
#pragma unroll
    for (int off = 32; off > 0; off >>= 1) {
        s  += __shfl_xor(s, off, 64);
        sq += __shfl_xor(sq, off, 64);
    }
    const float mean = s * (1.0f / 256.0f);
    const float var  = sq * (1.0f / 256.0f) - mean * mean;
    const float rstd = rsqrtf(var + 1e-5f);
    float4 yv; yv.x = v0; yv.y = v1; yv.z = v2; yv.w = v3;
    *reinterpret_cast<float4*>(&y[(size_t)t * C_ + c0]) = yv;
    float4 gr = *reinterpret_cast<const float4*>(&g[c0]);
    float4 br = *reinterpret_cast<const float4*>(&bb[c0]);
    ushort4 nv;
    nv.x = f2bf((v0 - mean) * rstd * gr.x + br.x);
    nv.y = f2bf((v1 - mean) * rstd * gr.y + br.y);
    nv.z = f2bf((v2 - mean) * rstd * gr.z + br.z);
    nv.w = f2bf((v3 - mean) * rstd * gr.w + br.w);
    *reinterpret_cast<ushort4*>(&xn[(size_t)t * C_ + c0]) = nv;
}

// ----------------------------------------------------------- MFMA bf16 GEMM v3
// M=NTOK, N=256, K=kdim (256 or 512). BM=64, BN=256, BK=32; 4 waves, wave w
// owns cols [w*64, w*64+64), acc[4][4]. One block per 64-row strip.
// mode: 0 plain->Cm, 1 +bias->Cm, 2 +bias+GELU->Cm, 5 Cf += acc + bias,
//       7 transposed store: Cm is [256][NTOK], Cm[col][row] = bf16(acc).
// LDS 40960 B = exactly 4 blocks/CU; launch_bounds(256,4) targets that.
__global__ __launch_bounds__(256, 4) void gemm_v3_kernel(
    const u16* __restrict__ A, const u16* __restrict__ A2,
    int bofs, int kdim,
    u16* __restrict__ Cm, float* __restrict__ Cf, const float* __restrict__ bias,
    int mode)
{
    // per buffer (u16 elems): A tile [64][32] at 0 (2048), B tile [256][32] at 2048 (8192)
    __shared__ __align__(16) u16 lds[2 * 10240];   // 40 KiB
    const int tid  = threadIdx.x;
    const int lane = tid & 63, wave = tid >> 6;
    const int lr = lane & 15, lq = lane >> 4;
    const int row0 = blockIdx.x * 64;
    const u16* Bt = &g_wT[bofs];

    const int s_row = lane >> 2;          // 0..15 within a 16-row segment
    const int s_kel = (lane & 3) * 8;     // k-element offset within 32

    floatx4 acc[4][4] = {};
    const int NK = kdim >> 5;
    int cur = 0;

    // ---- stage one K-step into buffer buf (5x global_load_lds per thread)
    auto STAGE = [&](int buf, int ks) {
        const int k0 = ks << 5;
        const u16* Asrc = A;
        int ka = k0;
        if (k0 >= 256) { Asrc = A2; ka = k0 - 256; }
        u16* lb = &lds[buf * 10240];
        // A: segment = wave (16 rows); lane-linear: elem = wave*512 + lane*8
        GL16(&Asrc[(size_t)(row0 + wave * 16 + s_row) * 256 + ka + s_kel],
             lb + wave * 512 + lane * 8);
        // B: segments s = wave*4+c (16 B^T-rows each)
#pragma unroll
        for (int c = 0; c < 4; ++c) {
            const int s = wave * 4 + c;
            GL16(&Bt[(size_t)(s * 16 + s_row) * kdim + k0 + s_kel],
                 lb + 2048 + s * 512 + lane * 8);
        }
    };

    STAGE(0, 0);
    __syncthreads();                      // drains vmcnt; buf0 ready

    for (int ks = 0; ks < NK; ++ks) {
        if (ks + 1 < NK) STAGE(cur ^ 1, ks + 1);   // issue-early: flies under compute
        const u16* lb = &lds[cur * 10240];
        bf16x8 af[4], bfv[4];
#pragma unroll
        for (int mt = 0; mt < 4; ++mt)
            af[mt] = *reinterpret_cast<const bf16x8*>(lb + (mt * 16 + lr) * 32 + lq * 8);
#pragma unroll
        for (int nt = 0; nt < 4; ++nt)
            bfv[nt] = *reinterpret_cast<const bf16x8*>(
                lb + 2048 + (wave * 64 + nt * 16 + lr) * 32 + lq * 8);
#pragma unroll
        for (int mt = 0; mt < 4; ++mt)
#pragma unroll
            for (int nt = 0; nt < 4; ++nt)
                acc[mt][nt] = __builtin_amdgcn_mfma_f32_16x16x32_bf16(
                    af[mt], bfv[nt], acc[mt][nt], 0, 0, 0);
        __syncthreads();                  // drains next-stage vmcnt + barrier
        cur ^= 1;
    }

    if (mode == 7) {
        // transposed bf16 store, direct from acc (8B per (mt,nt))
#pragma unroll
        for (int mt = 0; mt < 4; ++mt)
#pragma unroll
            for (int nt = 0; nt < 4; ++nt) {
                const int col = wave * 64 + nt * 16 + lr;
                const size_t tok = (size_t)row0 + mt * 16 + lq * 4;
                ushort4 st;
                st.x = f2bf(acc[mt][nt][0]);
                st.y = f2bf(acc[mt][nt][1]);
                st.z = f2bf(acc[mt][nt][2]);
                st.w = f2bf(acc[mt][nt][3]);
                *reinterpret_cast<ushort4*>(&Cm[(size_t)col * NTOK + tok]) = st;
            }
        return;
    }

    // ---- epilogue: per-wave LDS transpose slice (16 rows x 68 fp32, 4 passes)
    float* tw = reinterpret_cast<float*>(&lds[0]) + wave * (16 * 68);
#pragma unroll
    for (int mt = 0; mt < 4; ++mt) {
        asm volatile("s_waitcnt lgkmcnt(0)" ::: "memory");   // WAR vs prev pass reads
        __builtin_amdgcn_sched_barrier(0);
#pragma unroll
        for (int nt = 0; nt < 4; ++nt) {
            const int col = wave * 64 + nt * 16 + lr;
            const float bs = (mode != 0) ? bias[col] : 0.0f;
#pragma unroll
            for (int r = 0; r < 4; ++r) {
                float v = acc[mt][nt][r] + bs;
                if (mode == 2) v = 0.5f * v * (1.0f + erff(v * 0.70710678118654752f));
                tw[(lq * 4 + r) * 68 + nt * 16 + lr] = v;
            }
        }
        asm volatile("s_waitcnt lgkmcnt(0)" ::: "memory");   // writes visible to wave
        __builtin_amdgcn_sched_barrier(0);
        const int rrow = lane >> 2, grp = lane & 3;
        const float* src = &tw[rrow * 68 + grp * 16];
        float4 f0 = *reinterpret_cast<const float4*>(src + 0);
        float4 f1 = *reinterpret_cast<const float4*>(src + 4);
        float4 f2 = *reinterpret_cast<const float4*>(src + 8);
        float4 f3 = *reinterpret_cast<const float4*>(src + 12);
        const size_t gofs = (size_t)(row0 + mt * 16 + rrow) * 256 + wave * 64 + grp * 16;
        if (mode == 5) {
            float4* cp = reinterpret_cast<float4*>(&Cf[gofs]);
            float4 c0 = cp[0], c1 = cp[1], c2 = cp[2], c3 = cp[3];
            c0.x += f0.x; c0.y += f0.y; c0.z += f0.z; c0.w += f0.w;
            c1.x += f1.x; c1.y += f1.y; c1.z += f1.z; c1.w += f1.w;
            c2.x += f2.x; c2.y += f2.y; c2.z += f2.z; c2.w += f2.w;
            c3.x += f3.x; c3.y += f3.y; c3.z += f3.z; c3.w += f3.w;
            cp[0] = c0; cp[1] = c1; cp[2] = c2; cp[3] = c3;
        } else {
            const float tf[16] = {f0.x, f0.y, f0.z, f0.w, f1.x, f1.y, f1.z, f1.w,
                                  f2.x, f2.y, f2.z, f2.w, f3.x, f3.y, f3.z, f3.w};
            u16x8 o0, o1;
#pragma unroll
            for (int j = 0; j < 8; ++j) { o0[j] = f2bf(tf[j]); o1[j] = f2bf(tf[j + 8]); }
            *reinterpret_cast<u16x8*>(&Cm[gofs])     = o0;
            *reinterpret_cast<u16x8*>(&Cm[gofs + 8]) = o1;
        }
    }
}

// -------------------------------------------------------------- attention v4
// Barrier-free. block = (window wb, slice i), XCD-swizzled. 4 waves; wave w
// owns q-rows [16w,16w+16). All MFMA fragments direct from global (L2):
// Q/K rows, V^T rows. Bias from g_bexp (6x16B per lane). Softmax in log2
// domain, normalization deferred to O. Q and O are SEPARATE buffers
// (no store->load aliasing => compiler pipelines across heads).
// launch_bounds(256,4): VGPR cap 128 >= ~110 live, no spill (R5 lesson).
__global__ __launch_bounds__(256, 4) void attn_kernel(
    const u16* __restrict__ q, u16* __restrict__ o,
    const u16* __restrict__ kb, const u16* __restrict__ vT)
{
    __shared__ __align__(16) u16 sp[64][200];    // [q][key] P, bf16 (wave-private rows)

    const int bid = blockIdx.x;
    const int i  = (bid >> 3) & 3;
    const int wb = (bid & 7) + (bid >> 5) * 8;   // XCD = wb % 8
    const int tid = threadIdx.x;
    const int lane = tid & 63, wave = tid >> 6;
    const int lr = lane & 15, lq = lane >> 4;
    const size_t qbase = ((size_t)(wb * 256 + i * 64)) * C_;
    const size_t kwin  = ((size_t)(wb * 256)) * C_;
    const u16* bx = &g_bexp[((size_t)((i * 8) * 256) + (size_t)(wave * 64 + lq * 16 + lr)) * 48];

    for (int h = 0; h < 8; ++h) {
        const int hc = h * 32;
        // ---- bias fragment: 48 bf16 contiguous per lane
        u16x8 bvv[6];
        {
            const u16* bl = bx + (size_t)h * 256 * 48;
#pragma unroll
            for (int v = 0; v < 6; ++v)
                bvv[v] = *reinterpret_cast<const u16x8*>(bl + v * 8);
        }
        // ---- QK^T: A = own q rows, B = key rows (12 tiles), direct global
        const bf16x8 af = *reinterpret_cast<const bf16x8*>(
            &q[qbase + (size_t)(wave * 16 + lr) * C_ + hc + lq * 8]);
        floatx4 acc[12];
        __builtin_amdgcn_s_setprio(1);
#pragma unroll
        for (int t = 0; t < 12; ++t) {
            const int nrow = t * 16 + ((t * 16 >= i * 64) ? 64 : 0) + lr;
            const bf16x8 bk = *reinterpret_cast<const bf16x8*>(
                &kb[kwin + (size_t)nrow * C_ + hc + lq * 8]);
            acc[t] = __builtin_amdgcn_mfma_f32_16x16x32_bf16(
                af, bk, (floatx4){0.f, 0.f, 0.f, 0.f}, 0, 0, 0);
        }
        __builtin_amdgcn_s_setprio(0);
        // ---- scale (log2 domain) + bias, row max
        float mrow[4] = {-1e30f, -1e30f, -1e30f, -1e30f};
#pragma unroll
        for (int t = 0; t < 12; ++t)
#pragma unroll
            for (int r = 0; r < 4; ++r) {
                const int ii = t * 4 + r;
                const float v = fmaf(acc[t][r], QS2, bf2f((u16)bvv[ii >> 3][ii & 7]));
                acc[t][r] = v;
                mrow[r] = fmaxf(mrow[r], v);
            }
#pragma unroll
        for (int off = 8; off >= 1; off >>= 1)
#pragma unroll
            for (int r = 0; r < 4; ++r)
                mrow[r] = fmaxf(mrow[r], __shfl_xor(mrow[r], off, 64));
        // ---- exp2 + row sum (P left unnormalized; values in (0,1])
        float srow[4] = {0.f, 0.f, 0.f, 0.f};
#pragma unroll
        for (int t = 0; t < 12; ++t)
#pragma unroll
            for (int r = 0; r < 4; ++r) {
                const float e = exp2f(acc[t][r] - mrow[r]);
                acc[t][r] = e;
                srow[r] += e;
            }
#pragma unroll
        for (int off = 8; off >= 1; off >>= 1)
#pragma unroll
            for (int r = 0; r < 4; ++r)
                srow[r] += __shfl_xor(srow[r], off, 64);
#pragma unroll
        for (int r = 0; r < 4; ++r) srow[r] = 1.0f / srow[r];
        // ---- unnormalized P -> LDS (wave-private rows; no barrier needed)
#pragma unroll
        for (int t = 0; t < 12; ++t)
#pragma unroll
            for (int r = 0; r < 4; ++r)
                sp[wave * 16 + lq * 4 + r][t * 16 + lr] = f2bf(acc[t][r]);
        // ---- PV: A = P rows (LDS), B = V^T rows (direct global)
        floatx4 oacc[2];
        oacc[0] = (floatx4){0.f, 0.f, 0.f, 0.f};
        oacc[1] = (floatx4){0.f, 0.f, 0.f, 0.f};
        __builtin_amdgcn_s_setprio(1);
#pragma unroll
        for (int kc = 0; kc < 6; ++kc) {
            const bf16x8 pa = *reinterpret_cast<const bf16x8*>(
                &sp[wave * 16 + lr][kc * 32 + lq * 8]);
            const int kst = kc * 32 + lq * 8;
            const int nk0 = kst + ((kst >= i * 64) ? 64 : 0);
#pragma unroll
            for (int nt = 0; nt < 2; ++nt) {
                const bf16x8 bv = *reinterpret_cast<const bf16x8*>(
                    &vT[(size_t)(hc + nt * 16 + lr) * NTOK + wb * 256 + nk0]);
                oacc[nt] = __builtin_amdgcn_mfma_f32_16x16x32_bf16(pa, bv, oacc[nt], 0, 0, 0);
            }
        }
        __builtin_amdgcn_s_setprio(0);
        // ---- normalize O (deferred 1/srow) + write to o buffer (NOT q)
#pragma unroll
        for (int nt = 0; nt < 2; ++nt)
#pragma unroll
            for (int r = 0; r < 4; ++r)
                o[qbase + (size_t)(wave * 16 + lq * 4 + r) * C_ + hc + nt * 16 + lr] =
                    f2bf(oacc[nt][r] * srow[r]);
    }
}

// ----------------------------------------------------------------- launch
extern "C" void kernel_launch(void* const* d_in, const int* in_sizes, int n_in,
                              void* d_out, int out_size, void* d_ws, size_t ws_size,
                              hipStream_t stream) {
    const float* x    = (const float*)d_in[0];
    const float* ln1g = (const float*)d_in[1];
    const float* ln1b = (const float*)d_in[2];
    const float* ln2g = (const float*)d_in[3];
    const float* ln2b = (const float*)d_in[4];
    const float* wq   = (const float*)d_in[5];
    const float* wkv  = (const float*)d_in[6];
    const float* wp   = (const float*)d_in[7];
    const float* bp   = (const float*)d_in[8];
    const float* rpb  = (const float*)d_in[9];
    const float* w1   = (const float*)d_in[10];
    const float* b1   = (const float*)d_in[11];
    const float* w2   = (const float*)d_in[12];
    const float* b2   = (const float*)d_in[13];
    float* outf = (float*)d_out;
    u16*   outu = (u16*)d_out;          // bf16 scratch view: [k | vT]
    u16*   ws16 = (u16*)d_ws;

    u16* r0 = ws16;                     // xw -> q -> oproj -> h1
    u16* r1 = ws16 + R1_ELEMS;          // o -> xn -> h2 (in-place)
    u16* kbuf = outu;
    u16* vTb  = outu + R1_ELEMS;        // V^T [256][NTOK]

    // 0. convert weights to bf16 B^T into g_wT; expand bias table (once per launch)
    wcvt_kernel<<<256, 256, 0, stream>>>(wq,  256, 8, 0);
    wcvt_kernel<<<512, 256, 0, stream>>>(wkv, 512, 8, 65536);
    wcvt_kernel<<<256, 256, 0, stream>>>(wp,  256, 8, 196608);
    wcvt_kernel<<<512, 256, 0, stream>>>(w1,  512, 8, 262144);
    wcvt_kernel<<<512, 256, 0, stream>>>(w2,  256, 9, 393216);
    bexp_kernel<<<32, 256, 0, stream>>>(rpb);

    // 1. LN1 + window partition (fp32 -> bf16)
    ln_part_kernel<<<NTOK / 4, 256, 0, stream>>>(x, ln1g, ln1b, r0);

    // 2. k = xw @ wkv[:,0:256] -> kbuf; v^T = (xw @ wkv[:,256:512])^T -> vTb
    gemm_v3_kernel<<<NTOK / 64, 256, 0, stream>>>(r0, r0, 65536,  256, kbuf, nullptr, nullptr, 0);
    gemm_v3_kernel<<<NTOK / 64, 256, 0, stream>>>(r0, r0, 131072, 256, vTb,  nullptr, nullptr, 7);
    // 3. q = xw @ wq -> r0 (in-place)
    gemm_v3_kernel<<<NTOK / 64, 256, 0, stream>>>(r0, r0, 0, 256, r0, nullptr, nullptr, 0);

    // 4. attention: q (r0) -> o (r1); barrier-free, XCD-swizzled
    attn_kernel<<<2048, 256, 0, stream>>>(r0, r1, kbuf, vTb);

    // 5. oproj = o @ wp + bp: r1 -> r0 (q dead)
    gemm_v3_kernel<<<NTOK / 64, 256, 0, stream>>>(r1, r1, 196608, 256, r0, nullptr, bp, 1);

    // 6. y = x + reverse(oproj) -> d_out fp32 (k,vT dead); xn = LN2(y) -> r1 (o dead)
    resid_ln2_kernel<<<NTOK / 4, 256, 0, stream>>>(x, r0, ln2g, ln2b, outf, r1);

    // 7. MLP: h1 -> r0 (oproj dead), h2 -> r1 in-place over xn,
    //    then single K=512 GEMM: out = y + [h1|h2] @ w2^T + b2 (fp32 RMW once)
    gemm_v3_kernel<<<NTOK / 64, 256, 0, stream>>>(r1, r1, 262144, 256, r0, nullptr, b1,       2);
    gemm_v3_kernel<<<NTOK / 64, 256, 0, stream>>>(r1, r1, 327680, 256, r1, nullptr, b1 + 256, 2);
    gemm_v3_kernel<<<NTOK / 64, 256, 0, stream>>>(r0, r1, 393216, 512, nullptr, outf, b2,     5);
}